// Round 6
// baseline (129.317 us; speedup 1.0000x reference)
//
#include <hip/hip_runtime.h>
#include <hip/hip_bf16.h>

#define DEG 32
#define HID 256

typedef __bf16 bf16_t;
typedef bf16_t bf16x8 __attribute__((ext_vector_type(8)));
typedef float f32x16 __attribute__((ext_vector_type(16)));

// 10000^(-i/32), i = 0..31 (compile-time immediates after unroll)
constexpr float OMG[32] = {
    1.0f,           0.74989421f,    0.56234133f,    0.42169650f,
    0.31622777f,    0.23713737f,    0.17782794f,    0.13335214f,
    0.1f,           0.074989421f,   0.056234133f,   0.042169650f,
    0.031622777f,   0.023713737f,   0.017782794f,   0.013335214f,
    0.01f,          0.0074989421f,  0.0056234133f,  0.0042169650f,
    0.0031622777f,  0.0023713737f,  0.0017782794f,  0.0013335214f,
    0.001f,         0.00074989421f, 0.00056234133f, 0.00042169650f,
    0.00031622777f, 0.00023713737f, 0.00017782794f, 0.00013335214f};

// tanh-GELU: x * sigma(1.5957691*x*(1+0.044715*x^2))
// = x / (1 + exp(x * fma(x^2, -0.07136281, -1.5957691)))
__device__ __forceinline__ float gelu_fast(float x) {
  float t = fmaf(x * x, -0.071362814f, -1.5957691f);
  float e = __expf(x * t);
  return __fdividef(x, 1.0f + e);
}

__device__ __forceinline__ f32x16 mfma_bf16(bf16x8 a, bf16x8 b, f32x16 c) {
  return __builtin_amdgcn_mfma_f32_32x32x16_bf16(a, b, c, 0, 0, 0);
}

// ---- prep A: casts/transposes.
//  w1T[n][k]   = w1[k][n]            (256x256)
//  wpTa[o][n]  = wp[n][o]    n<256   (256x256)  A-operand for prep B
//  wpT2[o][256+kp] = wp[256+kp][o]   (bottom half of fused proj weight)
//  w2b[k][j]   = w2[k][j]            (row-major cast)
__global__ __launch_bounds__(256) void prep_a(
    const float* __restrict__ w1, const float* __restrict__ w2,
    const float* __restrict__ wp,
    bf16_t* __restrict__ w1T, bf16_t* __restrict__ wpTa,
    bf16_t* __restrict__ wpT2, bf16_t* __restrict__ w2b) {
  int tid = blockIdx.x * 256 + threadIdx.x;  // 262144 threads
  if (tid < 65536) {
    int n = tid >> 8, k = tid & 255;
    w1T[tid] = (bf16_t)w1[k * 256 + n];
  } else if (tid < 131072) {
    int t = tid - 65536;
    int o = t >> 8, n = t & 255;
    wpTa[t] = (bf16_t)wp[n * 256 + o];
  } else if (tid < 196608) {
    int t = tid - 131072;
    int o = t >> 8, kp = t & 255;
    wpT2[o * 512 + 256 + kp] = (bf16_t)wp[(256 + kp) * 256 + o];
  } else {
    int t = tid - 196608;
    w2b[t] = (bf16_t)w2[t];
  }
}

// ---- prep B: wpT2[o][j] = W2'[j][o] = sum_n w2[j][n] * wp[n][o]   (j<256)
__global__ __launch_bounds__(256) void prep_b(
    const bf16_t* __restrict__ wpTa, const bf16_t* __restrict__ w2b,
    bf16_t* __restrict__ wpT2) {
  const int tid = threadIdx.x;
  const int l = tid & 63;
  const int w = tid >> 6;
  const int wm = w >> 1, wn = w & 1;
  const int rm = blockIdx.x * 128 + wm * 64;  // o
  const int cn = blockIdx.y * 128 + wn * 64;  // j
  const int asel = l >> 5;
  const int lr = l & 31;
  const int r0 = rm + lr, r1 = rm + 32 + lr;
  const int c0 = cn + lr, c1 = cn + 32 + lr;

  f32x16 a00, a01, a10, a11;
#pragma unroll
  for (int q = 0; q < 16; ++q) { a00[q] = 0.f; a01[q] = 0.f; a10[q] = 0.f; a11[q] = 0.f; }
#pragma unroll 4
  for (int kk = 0; kk < 16; ++kk) {
    int k0 = kk * 16 + 8 * asel;
    bf16x8 fa0 = *(const bf16x8*)(wpTa + r0 * 256 + k0);
    bf16x8 fa1 = *(const bf16x8*)(wpTa + r1 * 256 + k0);
    bf16x8 fb0 = *(const bf16x8*)(w2b + c0 * 256 + k0);
    bf16x8 fb1 = *(const bf16x8*)(w2b + c1 * 256 + k0);
    a00 = mfma_bf16(fa0, fb0, a00);
    a01 = mfma_bf16(fa0, fb1, a01);
    a10 = mfma_bf16(fa1, fb0, a10);
    a11 = mfma_bf16(fa1, fb1, a11);
  }
#pragma unroll
  for (int rr = 0; rr < 16; ++rr) {
    int rowo = (rr & 3) + 8 * (rr >> 2) + 4 * asel;
    wpT2[(rm + rowo) * 512 + c0] = (bf16_t)a00[rr];
    wpT2[(rm + rowo) * 512 + c1] = (bf16_t)a01[rr];
    wpT2[(rm + 32 + rowo) * 512 + c0] = (bf16_t)a10[rr];
    wpT2[(rm + 32 + rowo) * 512 + c1] = (bf16_t)a11[rr];
  }
}

// ---- prep C: bfold[o] = bp[o] + sum_k b2[k] * wp[k][o]   (grid 32, parallel)
__global__ __launch_bounds__(256) void prep_c(
    const float* __restrict__ b2, const float* __restrict__ wp,
    const float* __restrict__ bp, float* __restrict__ bfold) {
  const int o = blockIdx.x * 8 + (threadIdx.x >> 5);
  const int kl = (threadIdx.x & 31) * 8;
  float s = 0.f;
#pragma unroll
  for (int k = 0; k < 8; ++k) s += b2[kl + k] * wp[(kl + k) * 256 + o];
  s += __shfl_xor(s, 16); s += __shfl_xor(s, 8); s += __shfl_xor(s, 4);
  s += __shfl_xor(s, 2); s += __shfl_xor(s, 1);
  if ((threadIdx.x & 31) == 0) bfold[o] = s + bp[o];
}

// ---- edge kernel: 2 supernodes/block (M=64, 32 KiB LDS, 4 blocks/CU).
__global__ __launch_bounds__(256, 4) void edge_mlp(
    const float* __restrict__ pos, const int* __restrict__ sup_idx,
    const int* __restrict__ src_idx,
    const bf16_t* __restrict__ w1T, const float* __restrict__ b1,
    bf16_t* __restrict__ cat) {
  __shared__ __attribute__((aligned(16))) bf16_t A[64 * 256];  // 32 KiB

  const int bid = blockIdx.x;
  const int tid = threadIdx.x;

  // ---- supernode abs-pos embed (ndim=3: 3*84, 42 freqs, 4 pad) -> cat[.,256:512]
  if (tid < 252) {
    const int j = tid;
    const int d = (j >= 84 ? 1 : 0) + (j >= 168 ? 1 : 0);
    const int jj = j - 84 * d;
    const int sc = (jj >= 42) ? 1 : 0;
    const int i = jj - 42 * sc;
    const float om = __expf(-0.21929381838038533f * (float)i);  // ln(1e4)/42
#pragma unroll
    for (int it = 0; it < 2; ++it) {
      const int srow = bid * 2 + it;
      const float p = pos[sup_idx[srow] * 3 + d];
      const float a = p * om;
      cat[srow * 512 + 256 + j] = (bf16_t)(sc ? __cosf(a) : __sinf(a));
    }
  } else {
#pragma unroll
    for (int it = 0; it < 2; ++it)
      cat[(bid * 2 + it) * 512 + 256 + tid] = (bf16_t)0.0f;  // pad cols 508..511
  }

  // ---- edge relpos embed: row r = tid>>2 (64 edges), quarter q = tid&3 = input dim
  {
    const int r = tid >> 2;
    const int q = tid & 3;
    const int e = bid * 64 + r;
    const int srci = src_idx[e];
    const int si = sup_idx[bid * 2 + (r >> 5)];
    const float dx = pos[si * 3 + 0] - pos[srci * 3 + 0];
    const float dy = pos[si * 3 + 1] - pos[srci * 3 + 1];
    const float dz = pos[si * 3 + 2] - pos[srci * 3 + 2];
    const float mg = sqrtf(dx * dx + dy * dy + dz * dz);
    const float rd = (q == 0) ? dx : (q == 1) ? dy : (q == 2) ? dz : mg;
    char* arow = (char*)A + r * 512;
    const int swz = (r & 31) << 4;
    const int cb0 = q << 3;  // 8 col-blocks (of 8 cols) per quarter
#pragma unroll
    for (int j = 0; j < 8; ++j) {
      bf16x8 v8;
#pragma unroll
      for (int je = 0; je < 8; ++je) {
        const float a = rd * OMG[(j & 3) * 8 + je];
        v8[je] = (bf16_t)((j >= 4) ? __cosf(a) : __sinf(a));
      }
      *(bf16x8*)(arow + (((cb0 + j) << 4) ^ swz)) = v8;
    }
  }
  __syncthreads();

  const int l = tid & 63, w = tid >> 6;
  const int hi = l >> 5, lc = l & 31;
  const char* Ab = (const char*)A;
  const int abase = lc * 512;
  const int swzl = lc << 4;

  f32x16 acc[2][2];
#pragma unroll
  for (int mt = 0; mt < 2; ++mt)
#pragma unroll
    for (int nt = 0; nt < 2; ++nt)
#pragma unroll
      for (int q = 0; q < 16; ++q) acc[mt][nt][q] = 0.0f;

  // ---- mm1: A(64x256) @ w1 ; wave w owns cols [64w, 64w+64)
  {
    const bf16_t* bp0 = w1T + (64 * w + lc) * 256 + 8 * hi;
    const bf16_t* bp1 = bp0 + 32 * 256;
#pragma unroll
    for (int kk = 0; kk < 16; ++kk) {
      const int koff = abase + ((kk * 32 + hi * 16) ^ swzl);
      bf16x8 a0 = *(const bf16x8*)(Ab + koff);
      bf16x8 a1 = *(const bf16x8*)(Ab + koff + 16384);
      bf16x8 f0 = *(const bf16x8*)(bp0 + kk * 16);
      bf16x8 f1 = *(const bf16x8*)(bp1 + kk * 16);
      acc[0][0] = mfma_bf16(a0, f0, acc[0][0]);
      acc[0][1] = mfma_bf16(a0, f1, acc[0][1]);
      acc[1][0] = mfma_bf16(a1, f0, acc[1][0]);
      acc[1][1] = mfma_bf16(a1, f1, acc[1][1]);
    }
  }

  // ---- gelu + segment mean (exactly 32 edges/supernode) -> cat[.,0:256]
  {
    const float bi0 = b1[64 * w + lc], bi1 = b1[64 * w + 32 + lc];
#pragma unroll
    for (int mt = 0; mt < 2; ++mt) {
      float s0 = 0.0f, s1 = 0.0f;
#pragma unroll
      for (int q = 0; q < 16; ++q) {
        s0 += gelu_fast(acc[mt][0][q] + bi0);
        s1 += gelu_fast(acc[mt][1][q] + bi1);
      }
      s0 += __shfl_xor(s0, 32);
      s1 += __shfl_xor(s1, 32);
      if (l < 32) {
        const int srow = bid * 2 + mt;
        cat[srow * 512 + 64 * w + lc] = (bf16_t)(s0 * 0.03125f);
        cat[srow * 512 + 64 * w + 32 + lc] = (bf16_t)(s1 * 0.03125f);
      }
    }
  }
}

// ---- fused projection: out = cat(8192x512) @ wpT2^T + bfold -> fp32
// 64x128 tile per block, grid(128,2) = 256 blocks; wave w owns 32 cols.
__global__ __launch_bounds__(256) void proj(
    const bf16_t* __restrict__ cat, const bf16_t* __restrict__ wpT2,
    const float* __restrict__ bfold, float* __restrict__ out) {
  const int tid = threadIdx.x;
  const int l = tid & 63, w = tid >> 6;
  const int hi = l >> 5, lc = l & 31;
  const int rm = blockIdx.x * 64;
  const int cn = blockIdx.y * 128 + w * 32;
  const int r0 = rm + lc, r1 = rm + 32 + lc;
  const int c0 = cn + lc;

  f32x16 a0, a1;
#pragma unroll
  for (int q = 0; q < 16; ++q) { a0[q] = 0.f; a1[q] = 0.f; }
#pragma unroll 8
  for (int kk = 0; kk < 32; ++kk) {
    int k0 = kk * 16 + 8 * hi;
    bf16x8 fa0 = *(const bf16x8*)(cat + r0 * 512 + k0);
    bf16x8 fa1 = *(const bf16x8*)(cat + r1 * 512 + k0);
    bf16x8 fb = *(const bf16x8*)(wpT2 + c0 * 512 + k0);
    a0 = mfma_bf16(fa0, fb, a0);
    a1 = mfma_bf16(fa1, fb, a1);
  }
  float bias = bfold[c0];
#pragma unroll
  for (int rr = 0; rr < 16; ++rr) {
    int rowo = (rr & 3) + 8 * (rr >> 2) + 4 * hi;
    out[(rm + rowo) * 256 + c0] = a0[rr] + bias;
    out[(rm + 32 + rowo) * 256 + c0] = a1[rr] + bias;
  }
}

extern "C" void kernel_launch(void* const* d_in, const int* in_sizes, int n_in,
                              void* d_out, int out_size, void* d_ws, size_t ws_size,
                              hipStream_t stream) {
  const float* pos = (const float*)d_in[0];
  const int* sup_idx = (const int*)d_in[1];
  const int* src_idx = (const int*)d_in[2];
  // d_in[3] = dst_seg: repeat(arange(NSUP), DEG) by construction; not needed
  const float* w1 = (const float*)d_in[4];
  const float* b1 = (const float*)d_in[5];
  const float* w2 = (const float*)d_in[6];
  const float* b2 = (const float*)d_in[7];
  const float* wp = (const float*)d_in[8];
  const float* bp = (const float*)d_in[9];

  char* ws = (char*)d_ws;
  bf16_t* w1T  = (bf16_t*)(ws);            // 128 KB
  bf16_t* w2b  = (bf16_t*)(ws + 131072);   // 128 KB
  bf16_t* wpTa = (bf16_t*)(ws + 262144);   // 128 KB
  bf16_t* wpT2 = (bf16_t*)(ws + 393216);   // 256 KB (256 x 512)
  float*  bfold = (float*)(ws + 655360);   // 1 KB
  bf16_t* cat  = (bf16_t*)(ws + 659456);   // 8192*512 bf16 = 8 MB
  float* out = (float*)d_out;

  if (ws_size < (size_t)(659456 + 8192 * 512 * 2)) return;  // workspace guard

  prep_a<<<dim3(1024), dim3(256), 0, stream>>>(w1, w2, wp, w1T, wpTa, wpT2, w2b);
  prep_b<<<dim3(2, 2), dim3(256), 0, stream>>>(wpTa, w2b, wpT2);
  prep_c<<<dim3(32), dim3(256), 0, stream>>>(b2, wp, bp, bfold);
  edge_mlp<<<dim3(4096), dim3(256), 0, stream>>>(pos, sup_idx, src_idx, w1T, b1, cat);
  proj<<<dim3(128, 2), dim3(256), 0, stream>>>(cat, wpT2, bfold, out);
}

// Round 7
// 111.137 us; speedup vs baseline: 1.1636x; 1.1636x over previous
//
#include <hip/hip_runtime.h>
#include <hip/hip_bf16.h>

#define DEG 32
#define HID 256

typedef __bf16 bf16_t;
typedef bf16_t bf16x8 __attribute__((ext_vector_type(8)));
typedef float f32x16 __attribute__((ext_vector_type(16)));

// 10000^(-i/32), i = 0..31
constexpr float OMG[32] = {
    1.0f,           0.74989421f,    0.56234133f,    0.42169650f,
    0.31622777f,    0.23713737f,    0.17782794f,    0.13335214f,
    0.1f,           0.074989421f,   0.056234133f,   0.042169650f,
    0.031622777f,   0.023713737f,   0.017782794f,   0.013335214f,
    0.01f,          0.0074989421f,  0.0056234133f,  0.0042169650f,
    0.0031622777f,  0.0023713737f,  0.0017782794f,  0.0013335214f,
    0.001f,         0.00074989421f, 0.00056234133f, 0.00042169650f,
    0.00031622777f, 0.00023713737f, 0.00017782794f, 0.00013335214f};

// tanh-GELU: x / (1 + exp(x * fma(x^2, -0.07136281, -1.5957691)))
__device__ __forceinline__ float gelu_fast(float x) {
  float t = fmaf(x * x, -0.071362814f, -1.5957691f);
  float e = __expf(x * t);
  return __fdividef(x, 1.0f + e);
}

__device__ __forceinline__ f32x16 mfma_bf16(bf16x8 a, bf16x8 b, f32x16 c) {
  return __builtin_amdgcn_mfma_f32_32x32x16_bf16(a, b, c, 0, 0, 0);
}

// ---- combo prep: bid<1024: weight casts/transposes; bid<2048: sup-embed; bid==2048: bias fold
__global__ __launch_bounds__(256) void prep_combo(
    const float* __restrict__ w1, const float* __restrict__ w2,
    const float* __restrict__ wp, const float* __restrict__ b2,
    const float* __restrict__ bp,
    const float* __restrict__ pos, const int* __restrict__ sup_idx,
    bf16_t* __restrict__ w1T, bf16_t* __restrict__ wpTa,
    bf16_t* __restrict__ wpT2, bf16_t* __restrict__ w2b,
    float* __restrict__ bfold, bf16_t* __restrict__ cat) {
  const int bid = blockIdx.x;
  const int tid = threadIdx.x;
  if (bid < 1024) {
    int t = bid * 256 + tid;  // 262144 threads over 4 jobs
    if (t < 65536) {
      int n = t >> 8, k = t & 255;
      w1T[t] = (bf16_t)w1[k * 256 + n];
    } else if (t < 131072) {
      int u = t - 65536;
      int o = u >> 8, n = u & 255;
      wpTa[u] = (bf16_t)wp[n * 256 + o];
    } else if (t < 196608) {
      int u = t - 131072;
      int o = u >> 8, kp = u & 255;
      wpT2[o * 512 + 256 + kp] = (bf16_t)wp[(256 + kp) * 256 + o];
    } else {
      int u = t - 196608;
      w2b[u] = (bf16_t)w2[u];
    }
  } else if (bid < 2048) {
    // supernode abs-pos embed (ndim=3: 3*84, 42 freqs, 4 pad) -> cat[.,256:512]
    const int row = (bid - 1024) * 8 + (tid >> 5);
    const int si = sup_idx[row];
    const int c0 = (tid & 31) * 8;
#pragma unroll
    for (int jj = 0; jj < 8; ++jj) {
      const int col = c0 + jj;
      float v = 0.0f;
      if (col < 252) {
        const int d = (col >= 84 ? 1 : 0) + (col >= 168 ? 1 : 0);
        const int t2 = col - 84 * d;
        const int sc = (t2 >= 42) ? 1 : 0;
        const int i = t2 - 42 * sc;
        const float om = __expf(-0.21929381838038533f * (float)i);  // ln(1e4)/42
        const float a = pos[si * 3 + d] * om;
        v = sc ? __cosf(a) : __sinf(a);
      }
      cat[row * 512 + 256 + col] = (bf16_t)v;
    }
  } else {
    // bfold[o] = bp[o] + sum_k b2[k] * wp[k][o]
    const int o = tid;
    float s = bp[o];
    for (int k = 0; k < 256; ++k) s += b2[k] * wp[k * 256 + o];
    bfold[o] = s;
  }
}

// ---- prep B: wpT2[o][j] = sum_n w2[j][n] * wp[n][o]   (j<256)
__global__ __launch_bounds__(256) void prep_b(
    const bf16_t* __restrict__ wpTa, const bf16_t* __restrict__ w2b,
    bf16_t* __restrict__ wpT2) {
  const int tid = threadIdx.x;
  const int l = tid & 63;
  const int w = tid >> 6;
  const int wm = w >> 1, wn = w & 1;
  const int rm = blockIdx.x * 128 + wm * 64;  // o
  const int cn = blockIdx.y * 128 + wn * 64;  // j
  const int asel = l >> 5;
  const int lr = l & 31;
  const int r0 = rm + lr, r1 = rm + 32 + lr;
  const int c0 = cn + lr, c1 = cn + 32 + lr;

  f32x16 a00, a01, a10, a11;
#pragma unroll
  for (int q = 0; q < 16; ++q) { a00[q] = 0.f; a01[q] = 0.f; a10[q] = 0.f; a11[q] = 0.f; }
#pragma unroll 4
  for (int kk = 0; kk < 16; ++kk) {
    int k0 = kk * 16 + 8 * asel;
    bf16x8 fa0 = *(const bf16x8*)(wpTa + r0 * 256 + k0);
    bf16x8 fa1 = *(const bf16x8*)(wpTa + r1 * 256 + k0);
    bf16x8 fb0 = *(const bf16x8*)(w2b + c0 * 256 + k0);
    bf16x8 fb1 = *(const bf16x8*)(w2b + c1 * 256 + k0);
    a00 = mfma_bf16(fa0, fb0, a00);
    a01 = mfma_bf16(fa0, fb1, a01);
    a10 = mfma_bf16(fa1, fb0, a10);
    a11 = mfma_bf16(fa1, fb1, a11);
  }
#pragma unroll
  for (int rr = 0; rr < 16; ++rr) {
    int rowo = (rr & 3) + 8 * (rr >> 2) + 4 * asel;
    wpT2[(rm + rowo) * 512 + c0] = (bf16_t)a00[rr];
    wpT2[(rm + rowo) * 512 + c1] = (bf16_t)a01[rr];
    wpT2[(rm + 32 + rowo) * 512 + c0] = (bf16_t)a10[rr];
    wpT2[(rm + 32 + rowo) * 512 + c1] = (bf16_t)a11[rr];
  }
}

// ---- edge kernel: 4 supernodes/block, 512 threads, K split in two 32 KiB halves.
__global__ __launch_bounds__(512, 4) void edge_mlp(
    const float* __restrict__ pos, const int* __restrict__ sup_idx,
    const int* __restrict__ src_idx,
    const bf16_t* __restrict__ w1T, const float* __restrict__ b1,
    bf16_t* __restrict__ cat) {
  __shared__ __attribute__((aligned(16))) bf16_t A[2][128 * 128];  // 2 x 32 KiB

  const int bid = blockIdx.x;
  const int tid = threadIdx.x;

  // per-edge relative position (4 threads per edge; redundant, L1-served)
  const int r = tid >> 2;   // edge row 0..127
  const int q = tid & 3;    // (dim-within-half, sin/cos): d = kh*2 + (q>>1), sc = q&1
  const int srci = src_idx[bid * 128 + r];
  const int si = sup_idx[bid * 4 + (r >> 5)];
  const float dx = pos[si * 3 + 0] - pos[srci * 3 + 0];
  const float dy = pos[si * 3 + 1] - pos[srci * 3 + 1];
  const float dz = pos[si * 3 + 2] - pos[srci * 3 + 2];
  const float mg = sqrtf(dx * dx + dy * dy + dz * dz);

  const int sc = q & 1;
  const int swz = (r & 7) << 4;
  const int wcol = (q >> 1) ? 1 : 0;

  // ---- embed khalf 0: cols 0..127 (dims dx, dy)
  {
    const float rd = wcol ? dy : dx;
    char* arow = (char*)A[0] + r * 256;
#pragma unroll
    for (int j = 0; j < 4; ++j) {
      bf16x8 v8;
#pragma unroll
      for (int e = 0; e < 8; ++e) {
        const float a = rd * OMG[j * 8 + e];
        v8[e] = (bf16_t)(sc ? __cosf(a) : __sinf(a));
      }
      *(bf16x8*)(arow + (((q << 6) + (j << 4)) ^ swz)) = v8;
    }
  }
  __syncthreads();

  // ---- embed khalf 1: cols 128..255 (dims dz, mag) -- overlaps mm0 below
  {
    const float rd = wcol ? mg : dz;
    char* arow = (char*)A[1] + r * 256;
#pragma unroll
    for (int j = 0; j < 4; ++j) {
      bf16x8 v8;
#pragma unroll
      for (int e = 0; e < 8; ++e) {
        const float a = rd * OMG[j * 8 + e];
        v8[e] = (bf16_t)(sc ? __cosf(a) : __sinf(a));
      }
      *(bf16x8*)(arow + (((q << 6) + (j << 4)) ^ swz)) = v8;
    }
  }

  const int l = tid & 63, w = tid >> 6;  // 8 waves, wave owns cols [32w, 32w+32)
  const int hi = l >> 5, lc = l & 31;
  const int swzl = (lc & 7) << 4;

  f32x16 acc[4];
#pragma unroll
  for (int mt = 0; mt < 4; ++mt)
#pragma unroll
    for (int p = 0; p < 16; ++p) acc[mt][p] = 0.0f;

  const bf16_t* bbase = w1T + (32 * w + lc) * 256 + hi * 8;

  // ---- mm khalf 0 (reads A[0]); B cols k in [0,128)
  {
    const char* Ab = (const char*)A[0] + lc * 256;
#pragma unroll
    for (int kk = 0; kk < 8; ++kk) {
      const int koff = (kk * 32 + hi * 16) ^ swzl;
      bf16x8 b = *(const bf16x8*)(bbase + kk * 16);
      bf16x8 a0 = *(const bf16x8*)(Ab + koff);
      bf16x8 a1 = *(const bf16x8*)(Ab + koff + 8192);
      bf16x8 a2 = *(const bf16x8*)(Ab + koff + 16384);
      bf16x8 a3 = *(const bf16x8*)(Ab + koff + 24576);
      acc[0] = mfma_bf16(a0, b, acc[0]);
      acc[1] = mfma_bf16(a1, b, acc[1]);
      acc[2] = mfma_bf16(a2, b, acc[2]);
      acc[3] = mfma_bf16(a3, b, acc[3]);
    }
  }
  __syncthreads();  // embed khalf 1 writes visible

  // ---- mm khalf 1 (reads A[1]); B cols k in [128,256)
  {
    const char* Ab = (const char*)A[1] + lc * 256;
#pragma unroll
    for (int kk = 0; kk < 8; ++kk) {
      const int koff = (kk * 32 + hi * 16) ^ swzl;
      bf16x8 b = *(const bf16x8*)(bbase + 128 + kk * 16);
      bf16x8 a0 = *(const bf16x8*)(Ab + koff);
      bf16x8 a1 = *(const bf16x8*)(Ab + koff + 8192);
      bf16x8 a2 = *(const bf16x8*)(Ab + koff + 16384);
      bf16x8 a3 = *(const bf16x8*)(Ab + koff + 24576);
      acc[0] = mfma_bf16(a0, b, acc[0]);
      acc[1] = mfma_bf16(a1, b, acc[1]);
      acc[2] = mfma_bf16(a2, b, acc[2]);
      acc[3] = mfma_bf16(a3, b, acc[3]);
    }
  }

  // ---- gelu + segment mean (exactly 32 edges/supernode) -> cat[.,0:256]
  {
    const float bi = b1[32 * w + lc];
#pragma unroll
    for (int mt = 0; mt < 4; ++mt) {
      float s = 0.0f;
#pragma unroll
      for (int p = 0; p < 16; ++p) s += gelu_fast(acc[mt][p] + bi);
      s += __shfl_xor(s, 32);
      if (l < 32) cat[(bid * 4 + mt) * 512 + 32 * w + lc] = (bf16_t)(s * 0.03125f);
    }
  }
}

// ---- fused projection: out = cat(8192x512) @ wpT2^T + bfold -> fp32
__global__ __launch_bounds__(256) void proj(
    const bf16_t* __restrict__ cat, const bf16_t* __restrict__ wpT2,
    const float* __restrict__ bfold, float* __restrict__ out) {
  const int tid = threadIdx.x;
  const int l = tid & 63, w = tid >> 6;
  const int hi = l >> 5, lc = l & 31;
  const int rm = blockIdx.x * 64;
  const int cn = blockIdx.y * 128 + w * 32;
  const int r0 = rm + lc, r1 = rm + 32 + lc;
  const int c0 = cn + lc;

  f32x16 a0, a1;
#pragma unroll
  for (int p = 0; p < 16; ++p) { a0[p] = 0.f; a1[p] = 0.f; }
#pragma unroll 8
  for (int kk = 0; kk < 32; ++kk) {
    int k0 = kk * 16 + 8 * hi;
    bf16x8 fa0 = *(const bf16x8*)(cat + r0 * 512 + k0);
    bf16x8 fa1 = *(const bf16x8*)(cat + r1 * 512 + k0);
    bf16x8 fb = *(const bf16x8*)(wpT2 + c0 * 512 + k0);
    a0 = mfma_bf16(fa0, fb, a0);
    a1 = mfma_bf16(fa1, fb, a1);
  }
  float bias = bfold[c0];
#pragma unroll
  for (int rr = 0; rr < 16; ++rr) {
    int rowo = (rr & 3) + 8 * (rr >> 2) + 4 * hi;
    out[(rm + rowo) * 256 + c0] = a0[rr] + bias;
    out[(rm + 32 + rowo) * 256 + c0] = a1[rr] + bias;
  }
}

extern "C" void kernel_launch(void* const* d_in, const int* in_sizes, int n_in,
                              void* d_out, int out_size, void* d_ws, size_t ws_size,
                              hipStream_t stream) {
  const float* pos = (const float*)d_in[0];
  const int* sup_idx = (const int*)d_in[1];
  const int* src_idx = (const int*)d_in[2];
  // d_in[3] = dst_seg: repeat(arange(NSUP), DEG) by construction; not needed
  const float* w1 = (const float*)d_in[4];
  const float* b1 = (const float*)d_in[5];
  const float* w2 = (const float*)d_in[6];
  const float* b2 = (const float*)d_in[7];
  const float* wp = (const float*)d_in[8];
  const float* bp = (const float*)d_in[9];

  char* ws = (char*)d_ws;
  bf16_t* w1T  = (bf16_t*)(ws);            // 128 KB
  bf16_t* w2b  = (bf16_t*)(ws + 131072);   // 128 KB
  bf16_t* wpTa = (bf16_t*)(ws + 262144);   // 128 KB
  bf16_t* wpT2 = (bf16_t*)(ws + 393216);   // 256 KB (256 x 512)
  float*  bfold = (float*)(ws + 655360);   // 1 KB
  bf16_t* cat  = (bf16_t*)(ws + 659456);   // 8192*512 bf16 = 8 MB
  float* out = (float*)d_out;

  if (ws_size < (size_t)(659456 + 8192 * 512 * 2)) return;  // workspace guard

  prep_combo<<<dim3(2049), dim3(256), 0, stream>>>(
      w1, w2, wp, b2, bp, pos, sup_idx, w1T, wpTa, wpT2, w2b, bfold, cat);
  prep_b<<<dim3(2, 2), dim3(256), 0, stream>>>(wpTa, w2b, wpT2);
  edge_mlp<<<dim3(2048), dim3(512), 0, stream>>>(pos, sup_idx, src_idx, w1T, b1, cat);
  proj<<<dim3(128, 2), dim3(256), 0, stream>>>(cat, wpT2, bfold, out);
}

// Round 8
// 109.358 us; speedup vs baseline: 1.1825x; 1.0163x over previous
//
#include <hip/hip_runtime.h>
#include <hip/hip_bf16.h>

typedef __bf16 bf16_t;
typedef bf16_t bf16x8 __attribute__((ext_vector_type(8)));
typedef float f32x16 __attribute__((ext_vector_type(16)));

// 10000^(-i/32) = 10^(-i/8), i = 0..15  (i>=16 handled via rd*0.01)
constexpr float OMG[16] = {
    1.0f,        0.74989421f, 0.56234133f, 0.42169650f,
    0.31622777f, 0.23713737f, 0.17782794f, 0.13335214f,
    0.1f,        0.074989421f, 0.056234133f, 0.042169650f,
    0.031622777f, 0.023713737f, 0.017782794f, 0.013335214f};

__device__ __forceinline__ f32x16 mfma_bf16(bf16x8 a, bf16x8 b, f32x16 c) {
  return __builtin_amdgcn_mfma_f32_32x32x16_bf16(a, b, c, 0, 0, 0);
}

// ---- prep1: LDS-tiled transposes + w2 cast + sup-embed + bias fold
__global__ __launch_bounds__(256) void prep1(
    const float* __restrict__ w1, const float* __restrict__ w2,
    const float* __restrict__ wp, const float* __restrict__ b2,
    const float* __restrict__ bp, const float* __restrict__ pos,
    const int* __restrict__ sup_idx,
    bf16_t* __restrict__ w1T, bf16_t* __restrict__ wpTa,
    bf16_t* __restrict__ wpT2, bf16_t* __restrict__ w2b,
    float* __restrict__ bfold, bf16_t* __restrict__ cat) {
  const int bid = blockIdx.x;
  const int tid = threadIdx.x;
  if (bid < 24) {
    // transpose a 32-row band of a 256x256 fp32 matrix into bf16 [col][row]
    __shared__ float T[32][257];
    const float* src; bf16_t* dst; int stride, off;
    const int band = (bid & 7) * 32;
    if (bid < 8)       { src = w1;         dst = w1T;  stride = 256; off = 0; }
    else if (bid < 16) { src = wp;         dst = wpTa; stride = 256; off = 0; }
    else               { src = wp + 65536; dst = wpT2; stride = 512; off = 256; }
#pragma unroll
    for (int it = 0; it < 32; ++it)
      T[it][tid] = src[(band + it) * 256 + tid];
    __syncthreads();
#pragma unroll
    for (int g2 = 0; g2 < 4; ++g2) {
      bf16x8 v;
#pragma unroll
      for (int e = 0; e < 8; ++e) v[e] = (bf16_t)T[g2 * 8 + e][tid];
      *(bf16x8*)(dst + tid * stride + off + band + g2 * 8) = v;
    }
  } else if (bid < 32) {
    // w2b: straight fp32 -> bf16 cast (row-major)
    const int base = (bid - 24) * 8192;
#pragma unroll
    for (int it = 0; it < 32; ++it) {
      const int idx = base + it * 256 + tid;
      w2b[idx] = (bf16_t)w2[idx];
    }
  } else if (bid < 288) {
    // supernode abs-pos embed (ndim=3: 3*84, 42 freqs, 4 pad) -> cat[.,256:512]
    const int col = tid;
    int d = 0, sc = 0;
    float om = 0.0f;
    if (col < 252) {
      d = (col >= 84 ? 1 : 0) + (col >= 168 ? 1 : 0);
      const int t2 = col - 84 * d;
      sc = (t2 >= 42) ? 1 : 0;
      const int i2 = t2 - 42 * sc;
      om = __expf(-0.21929381838038533f * (float)i2);  // ln(1e4)/42
    }
    const int r0 = (bid - 32) * 32;
    for (int it = 0; it < 32; ++it) {
      const int row = r0 + it;
      float v = 0.0f;
      if (col < 252) {
        const float a = pos[sup_idx[row] * 3 + d] * om;
        v = sc ? __cosf(a) : __sinf(a);
      }
      cat[row * 512 + 256 + col] = (bf16_t)v;
    }
  } else {
    // bfold[o] = bp[o] + sum_k b2[k] * wp[k][o]
    const int o = (bid - 288) * 8 + (tid >> 5);
    const int kl = (tid & 31) * 8;
    float s = 0.f;
#pragma unroll
    for (int k = 0; k < 8; ++k) s += b2[kl + k] * wp[(kl + k) * 256 + o];
    s += __shfl_xor(s, 16); s += __shfl_xor(s, 8); s += __shfl_xor(s, 4);
    s += __shfl_xor(s, 2); s += __shfl_xor(s, 1);
    if ((tid & 31) == 0) bfold[o] = s + bp[o];
  }
}

// ---- prep B: wpT2[o][j] = sum_n w2[j][n] * wp[n][o]   (j<256)
__global__ __launch_bounds__(256) void prep_b(
    const bf16_t* __restrict__ wpTa, const bf16_t* __restrict__ w2b,
    bf16_t* __restrict__ wpT2) {
  const int tid = threadIdx.x;
  const int l = tid & 63;
  const int w = tid >> 6;
  const int wm = w >> 1, wn = w & 1;
  const int rm = blockIdx.x * 128 + wm * 64;  // o
  const int cn = blockIdx.y * 128 + wn * 64;  // j
  const int asel = l >> 5;
  const int lr = l & 31;
  const int r0 = rm + lr, r1 = rm + 32 + lr;
  const int c0 = cn + lr, c1 = cn + 32 + lr;

  f32x16 a00, a01, a10, a11;
#pragma unroll
  for (int q = 0; q < 16; ++q) { a00[q] = 0.f; a01[q] = 0.f; a10[q] = 0.f; a11[q] = 0.f; }
#pragma unroll 4
  for (int kk = 0; kk < 16; ++kk) {
    int k0 = kk * 16 + 8 * asel;
    bf16x8 fa0 = *(const bf16x8*)(wpTa + r0 * 256 + k0);
    bf16x8 fa1 = *(const bf16x8*)(wpTa + r1 * 256 + k0);
    bf16x8 fb0 = *(const bf16x8*)(w2b + c0 * 256 + k0);
    bf16x8 fb1 = *(const bf16x8*)(w2b + c1 * 256 + k0);
    a00 = mfma_bf16(fa0, fb0, a00);
    a01 = mfma_bf16(fa0, fb1, a01);
    a10 = mfma_bf16(fa1, fb0, a10);
    a11 = mfma_bf16(fa1, fb1, a11);
  }
#pragma unroll
  for (int rr = 0; rr < 16; ++rr) {
    int rowo = (rr & 3) + 8 * (rr >> 2) + 4 * asel;
    wpT2[(rm + rowo) * 512 + c0] = (bf16_t)a00[rr];
    wpT2[(rm + rowo) * 512 + c1] = (bf16_t)a01[rr];
    wpT2[(rm + 32 + rowo) * 512 + c0] = (bf16_t)a10[rr];
    wpT2[(rm + 32 + rowo) * 512 + c1] = (bf16_t)a11[rr];
  }
}

// ---- edge kernel: 1 wave = 1 supernode (M=32). A-fragments generated
// directly in registers (no LDS round-trip); w1T staged per k-half in LDS.
__global__ __launch_bounds__(256, 2) void edge_mlp(
    const float* __restrict__ pos, const int* __restrict__ sup_idx,
    const int* __restrict__ src_idx,
    const bf16_t* __restrict__ w1T, const float* __restrict__ b1,
    bf16_t* __restrict__ cat) {
  __shared__ __attribute__((aligned(16))) bf16_t B[256 * 128];  // 64 KiB (one k-half)

  const int tid = threadIdx.x;
  const int l = tid & 63, w = tid >> 6;
  const int hi = l >> 5, lc = l & 31;
  const int s = blockIdx.x * 4 + w;  // supernode of this wave

  // rel-pos of this lane's edge (row lc); hi=0/1 lanes redundant (L1-served)
  const int si = sup_idx[s];
  const int srci = src_idx[s * 32 + lc];
  const float dx = pos[si * 3 + 0] - pos[srci * 3 + 0];
  const float dy = pos[si * 3 + 1] - pos[srci * 3 + 1];
  const float dz = pos[si * 3 + 2] - pos[srci * 3 + 2];
  const float mg = sqrtf(dx * dx + dy * dy + dz * dz);
  const float rdv[8] = {dx, dx * 0.01f, dy, dy * 0.01f,
                        dz, dz * 0.01f, mg, mg * 0.01f};

  // lane-constant omegas: OMG[8*hi + e]
  float omg[8];
#pragma unroll
  for (int e = 0; e < 8; ++e) omg[e] = hi ? OMG[8 + e] : OMG[e];

  float bi[8];
#pragma unroll
  for (int nt = 0; nt < 8; ++nt) bi[nt] = b1[32 * nt + lc];

  f32x16 acc[8];
#pragma unroll
  for (int nt = 0; nt < 8; ++nt)
#pragma unroll
    for (int p = 0; p < 16; ++p) acc[nt][p] = 0.0f;

  const int wswz = (lc & 15) << 4;

#pragma unroll
  for (int h = 0; h < 2; ++h) {
    if (h) __syncthreads();  // all reads of previous half done
    // stage w1T[:, h*128 .. h*128+128) into B (swizzled, 2 batches of 8)
#pragma unroll
    for (int bh = 0; bh < 2; ++bh) {
      bf16x8 st[8];
#pragma unroll
      for (int p = 0; p < 8; ++p) {
        const int g = (bh * 8 + p) * 256 + tid;
        const int n = g >> 4, slot = g & 15;
        st[p] = *(const bf16x8*)(w1T + n * 256 + h * 128 + slot * 8);
      }
#pragma unroll
      for (int p = 0; p < 8; ++p) {
        const int g = (bh * 8 + p) * 256 + tid;
        const int n = g >> 4, slot = g & 15;
        *(bf16x8*)((char*)B + n * 256 + ((slot * 16) ^ ((n & 15) << 4))) = st[p];
      }
    }
    __syncthreads();

#pragma unroll
    for (int kk = 0; kk < 8; ++kk) {
      const int gkk = h * 8 + kk;         // global k-step 0..15
      const int koff = (kk * 32 + 16 * hi) ^ wswz;
      // issue B-frag loads first (hide LDS latency under embed VALU)
      bf16x8 bfr[8];
#pragma unroll
      for (int nt = 0; nt < 8; ++nt)
        bfr[nt] = *(const bf16x8*)((const char*)B + (32 * nt + lc) * 256 + koff);
      // A-fragment: embed cols 16*gkk + 8*hi + e of row lc, in registers
      const float rdk = rdv[(gkk >> 2) * 2 + (gkk & 1)];
      const int sc = (gkk >> 1) & 1;
      bf16x8 a;
#pragma unroll
      for (int e = 0; e < 8; ++e) {
        const float ang = rdk * omg[e];
        a[e] = (bf16_t)(sc ? __cosf(ang) : __sinf(ang));
      }
#pragma unroll
      for (int nt = 0; nt < 8; ++nt)
        acc[nt] = mfma_bf16(a, bfr[nt], acc[nt]);
    }
  }

  // gelu + segment mean (exactly 32 edges) -> cat[s, 0:256]
#pragma unroll
  for (int nt = 0; nt < 8; ++nt) {
    float ss = 0.0f;
#pragma unroll
    for (int p = 0; p < 16; ++p) {
      const float x = acc[nt][p] + bi[nt];
      const float t = fmaf(x * x, -0.071362814f, -1.5957691f);
      const float e = __expf(x * t);
      ss += __fdividef(x, 1.0f + e);
    }
    ss += __shfl_xor(ss, 32);
    if (hi == 0) cat[s * 512 + 32 * nt + lc] = (bf16_t)(ss * 0.03125f);
  }
}

// ---- fused projection: out = cat(8192x512) @ wpT2^T + bfold -> fp32
__global__ __launch_bounds__(256) void proj(
    const bf16_t* __restrict__ cat, const bf16_t* __restrict__ wpT2,
    const float* __restrict__ bfold, float* __restrict__ out) {
  const int tid = threadIdx.x;
  const int l = tid & 63, w = tid >> 6;
  const int hi = l >> 5, lc = l & 31;
  const int rm = blockIdx.x * 64;
  const int cn = blockIdx.y * 128 + w * 32;
  const int r0 = rm + lc, r1 = rm + 32 + lc;
  const int c0 = cn + lc;

  f32x16 a0, a1;
#pragma unroll
  for (int p = 0; p < 16; ++p) { a0[p] = 0.f; a1[p] = 0.f; }
#pragma unroll 8
  for (int kk = 0; kk < 32; ++kk) {
    int k0 = kk * 16 + 8 * hi;
    bf16x8 fa0 = *(const bf16x8*)(cat + r0 * 512 + k0);
    bf16x8 fa1 = *(const bf16x8*)(cat + r1 * 512 + k0);
    bf16x8 fb = *(const bf16x8*)(wpT2 + c0 * 512 + k0);
    a0 = mfma_bf16(fa0, fb, a0);
    a1 = mfma_bf16(fa1, fb, a1);
  }
  float bias = bfold[c0];
#pragma unroll
  for (int rr = 0; rr < 16; ++rr) {
    int rowo = (rr & 3) + 8 * (rr >> 2) + 4 * hi;
    out[(rm + rowo) * 256 + c0] = a0[rr] + bias;
    out[(rm + 32 + rowo) * 256 + c0] = a1[rr] + bias;
  }
}

extern "C" void kernel_launch(void* const* d_in, const int* in_sizes, int n_in,
                              void* d_out, int out_size, void* d_ws, size_t ws_size,
                              hipStream_t stream) {
  const float* pos = (const float*)d_in[0];
  const int* sup_idx = (const int*)d_in[1];
  const int* src_idx = (const int*)d_in[2];
  // d_in[3] = dst_seg: repeat(arange(NSUP), DEG) by construction; not needed
  const float* w1 = (const float*)d_in[4];
  const float* b1 = (const float*)d_in[5];
  const float* w2 = (const float*)d_in[6];
  const float* b2 = (const float*)d_in[7];
  const float* wp = (const float*)d_in[8];
  const float* bp = (const float*)d_in[9];

  char* ws = (char*)d_ws;
  bf16_t* w1T  = (bf16_t*)(ws);            // 128 KB
  bf16_t* w2b  = (bf16_t*)(ws + 131072);   // 128 KB
  bf16_t* wpTa = (bf16_t*)(ws + 262144);   // 128 KB
  bf16_t* wpT2 = (bf16_t*)(ws + 393216);   // 256 KB (256 x 512)
  float*  bfold = (float*)(ws + 655360);   // 1 KB
  bf16_t* cat  = (bf16_t*)(ws + 659456);   // 8192*512 bf16 = 8 MB
  float* out = (float*)d_out;

  if (ws_size < (size_t)(659456 + 8192 * 512 * 2)) return;  // workspace guard

  prep1<<<dim3(320), dim3(256), 0, stream>>>(
      w1, w2, wp, b2, bp, pos, sup_idx, w1T, wpTa, wpT2, w2b, bfold, cat);
  prep_b<<<dim3(2, 2), dim3(256), 0, stream>>>(wpTa, w2b, wpT2);
  edge_mlp<<<dim3(2048), dim3(256), 0, stream>>>(pos, sup_idx, src_idx, w1T, b1, cat);
  proj<<<dim3(128, 2), dim3(256), 0, stream>>>(cat, wpT2, bfold, out);
}